// Round 1
// baseline (341.168 us; speedup 1.0000x reference)
//
#include <hip/hip_runtime.h>
#include <hip/hip_bf16.h>
#include <math.h>

// Problem constants
#define PS    32768
#define DIN   1024
#define DMID  512
#define DATT  128
#define KMASK 16384
#define LKEEP 16384

typedef unsigned short u16;
typedef __attribute__((ext_vector_type(8))) short short8;
typedef __attribute__((ext_vector_type(4))) float f32x4;

__device__ __forceinline__ u16 f2bf(float f){
  unsigned x = __float_as_uint(f);
  unsigned r = (x + 0x7fffu + ((x >> 16) & 1u)) >> 16;  // RNE
  return (u16)r;
}
__device__ __forceinline__ float bf2f(u16 u){
  return __uint_as_float(((unsigned)u) << 16);
}
// monotonic key: larger float -> larger unsigned
__device__ __forceinline__ unsigned fkey(float f){
  unsigned b = __float_as_uint(f);
  return (b & 0x80000000u) ? ~b : (b | 0x80000000u);
}

#define GLDS16(g,l) __builtin_amdgcn_global_load_lds( \
    (const __attribute__((address_space(1))) void*)(g), \
    (__attribute__((address_space(3))) void*)(l), 16, 0, 0)

// ---------------------------------------------------------------------------
// Kernel 1: exact top-K selection (radix-256 select, 4 passes) + compaction.
// keep set = complement of top-KMASK by (value desc, index asc).
// ---------------------------------------------------------------------------
__global__ __launch_bounds__(1024) void k_select(const float* __restrict__ attn,
                                                 int* __restrict__ keep_ids){
  __shared__ unsigned hist[256];
  __shared__ int scan[1024];
  __shared__ unsigned sh_prefix;
  __shared__ int sh_k;
  const int t = threadIdx.x;

  unsigned prefix = 0;
  int k = KMASK;
  for (int p = 0; p < 4; p++){
    const int shift = 24 - 8*p;
    if (t < 256) hist[t] = 0u;
    __syncthreads();
    for (int i = t; i < PS; i += 1024){
      unsigned u = fkey(attn[i]);
      bool match = (p == 0) || ((u >> (shift + 8)) == prefix);
      if (match) atomicAdd(&hist[(u >> shift) & 255u], 1u);
    }
    __syncthreads();
    if (t == 0){
      int cum = 0; int digit = 0;
      for (int b = 255; b >= 0; b--){
        int c = (int)hist[b];
        if (cum + c >= k){ digit = b; k -= cum; break; }
        cum += c;
      }
      sh_prefix = (prefix << 8) | (unsigned)digit;
      sh_k = k;
    }
    __syncthreads();
    prefix = sh_prefix; k = sh_k;
    __syncthreads();
  }
  const unsigned C = prefix;   // cutoff key (KMASK-th largest)
  const int r = k;             // # of ==C elements that go to the MASKED set (smallest indices)

  // chunk of 32 consecutive indices per thread (keeps index order for tie ranks)
  const int base_i = t * 32;

  // pass A: count equals per chunk
  int local_eq = 0;
  for (int j = 0; j < 32; j++){
    if (fkey(attn[base_i + j]) == C) local_eq++;
  }
  scan[t] = local_eq; __syncthreads();
  for (int off = 1; off < 1024; off <<= 1){
    int v = (t >= off) ? scan[t - off] : 0;
    __syncthreads();
    scan[t] += v;
    __syncthreads();
  }
  const int eqbase = scan[t] - local_eq;
  __syncthreads();

  // pass B: kept flags
  unsigned kmask = 0; int local_keep = 0; int eqr = eqbase;
  for (int j = 0; j < 32; j++){
    unsigned u = fkey(attn[base_i + j]);
    bool kept;
    if (u < C) kept = true;
    else if (u == C){ kept = (eqr >= r); eqr++; }
    else kept = false;
    if (kept){ kmask |= (1u << j); local_keep++; }
  }
  scan[t] = local_keep; __syncthreads();
  for (int off = 1; off < 1024; off <<= 1){
    int v = (t >= off) ? scan[t - off] : 0;
    __syncthreads();
    scan[t] += v;
    __syncthreads();
  }
  int wbase = scan[t] - local_keep;

  // pass C: write compacted ids (ascending order)
  for (int j = 0; j < 32; j++){
    if (kmask & (1u << j)) keep_ids[wbase++] = base_i + j;
  }
}

// ---------------------------------------------------------------------------
// Transpose + f32->bf16 convert: out[c][r] = bf16(in[r][c]).  R,C multiples of 32.
// ---------------------------------------------------------------------------
__global__ __launch_bounds__(256) void k_tcvt(const float* __restrict__ in,
                                              u16* __restrict__ out, int R, int C){
  __shared__ float tile[32][33];
  const int tx = threadIdx.x & 31, ty = threadIdx.x >> 5;  // 32 x 8
  const int c0 = blockIdx.x * 32, r0 = blockIdx.y * 32;
  for (int i = 0; i < 32; i += 8)
    tile[ty + i][tx] = in[(size_t)(r0 + ty + i) * C + c0 + tx];
  __syncthreads();
  for (int i = 0; i < 32; i += 8)
    out[(size_t)(c0 + ty + i) * R + r0 + tx] = f2bf(tile[tx][ty + i]);
}

// ---------------------------------------------------------------------------
// Gather kept rows of x and convert to bf16. One block per kept row.
// ---------------------------------------------------------------------------
__global__ __launch_bounds__(256) void k_gather(const float* __restrict__ x,
                                                const int* __restrict__ keep,
                                                u16* __restrict__ xbf){
  const int j = blockIdx.x;
  const int id = keep[j];
  const float4 v = ((const float4*)(x + (size_t)id * DIN))[threadIdx.x];
  ushort4 pk;
  pk.x = f2bf(v.x); pk.y = f2bf(v.y); pk.z = f2bf(v.z); pk.w = f2bf(v.w);
  ((ushort4*)(xbf + (size_t)j * DIN))[threadIdx.x] = pk;
}

// ---------------------------------------------------------------------------
// GEMM1: h = relu(x_k @ W_emb + b_emb)  [16384 x 1024] x [1024 x 512] -> bf16
// 128x128 tile, BK=32, 4 waves (2x2 of 64x64), mfma 16x16x32 bf16.
// A-LDS [128][32] row-major, B-LDS [128 cols][32 k] (W pre-transposed).
// ---------------------------------------------------------------------------
__global__ __launch_bounds__(256) void k_gemm1(const u16* __restrict__ xbf,
                                               const u16* __restrict__ wet,
                                               const float* __restrict__ bemb,
                                               u16* __restrict__ hbf){
  __shared__ __align__(16) u16 As[128 * 32];
  __shared__ __align__(16) u16 Bs[128 * 32];
  const int t = threadIdx.x;
  const int wid = t >> 6, lane = t & 63;
  const int g = lane >> 4, li = lane & 15;
  const int brow = blockIdx.y * 128, bcol = blockIdx.x * 128;
  const int wrow0 = (wid >> 1) * 64, wcol0 = (wid & 1) * 64;

  f32x4 acc[4][4];
  for (int m = 0; m < 4; m++)
    for (int n = 0; n < 4; n++)
      acc[m][n] = (f32x4){0.f, 0.f, 0.f, 0.f};

  const int r4 = lane >> 2, c4 = lane & 3;
  const u16* gA = xbf + ((size_t)(brow + wid * 32 + r4) * DIN + c4 * 8);
  const u16* gB = wet + ((size_t)(bcol + wid * 32 + r4) * DIN + c4 * 8);
  u16* lA = As + wid * 1024;   // wave-uniform LDS base; HW adds lane*16B
  u16* lB = Bs + wid * 1024;

  for (int k0 = 0; k0 < DIN; k0 += 32){
    GLDS16(gA + k0,            lA);        // rows wid*32 + 0..15
    GLDS16(gA + 16 * DIN + k0, lA + 512);  // rows wid*32 + 16..31
    GLDS16(gB + k0,            lB);
    GLDS16(gB + 16 * DIN + k0, lB + 512);
    __syncthreads();
    short8 a[4], b[4];
    for (int m = 0; m < 4; m++)
      a[m] = *(const short8*)&As[(wrow0 + m * 16 + li) * 32 + g * 8];
    for (int n = 0; n < 4; n++)
      b[n] = *(const short8*)&Bs[(wcol0 + n * 16 + li) * 32 + g * 8];
    for (int m = 0; m < 4; m++)
      for (int n = 0; n < 4; n++)
        acc[m][n] = __builtin_amdgcn_mfma_f32_16x16x32_bf16(a[m], b[n], acc[m][n], 0, 0, 0);
    __syncthreads();
  }

  for (int n = 0; n < 4; n++){
    const int col = bcol + wcol0 + n * 16 + li;
    const float be = bemb[col];
    for (int m = 0; m < 4; m++){
      const int row0 = brow + wrow0 + m * 16 + g * 4;
      f32x4 v = acc[m][n];
      for (int r = 0; r < 4; r++){
        float val = v[r] + be;
        if (val < 0.f) val = 0.f;
        hbf[(size_t)(row0 + r) * DMID + col] = f2bf(val);
      }
    }
  }
}

// ---------------------------------------------------------------------------
// GEMM2 + fused exact-gelu + W_a2 dot: s[j] = gelu(h_j @ W_a1 + b_a1) . W_a2 + b_a2
// M-tile 64, N=128 (full), BK=32, 4 waves (2 rows x 2 cols of 32x64).
// ---------------------------------------------------------------------------
__global__ __launch_bounds__(256) void k_gemm2(const u16* __restrict__ hbf,
                                               const u16* __restrict__ wa1t,
                                               const float* __restrict__ ba1,
                                               const float* __restrict__ wa2,
                                               const float* __restrict__ ba2,
                                               float* __restrict__ s_out){
  __shared__ __align__(16) u16 As[64 * 32];
  __shared__ __align__(16) u16 Bs[128 * 32];
  const int t = threadIdx.x;
  const int wid = t >> 6, lane = t & 63;
  const int g = lane >> 4, li = lane & 15;
  const int brow = blockIdx.x * 64;
  const int wrow0 = (wid >> 1) * 32, wcol0 = (wid & 1) * 64;

  f32x4 acc[2][4];
  for (int m = 0; m < 2; m++)
    for (int n = 0; n < 4; n++)
      acc[m][n] = (f32x4){0.f, 0.f, 0.f, 0.f};

  const int r4 = lane >> 2, c4 = lane & 3;
  const u16* gA = hbf  + ((size_t)(brow + wid * 16 + r4) * DMID + c4 * 8);
  const u16* gB = wa1t + ((size_t)(wid * 32 + r4) * DMID + c4 * 8);
  u16* lA = As + wid * 512;
  u16* lB = Bs + wid * 1024;

  for (int k0 = 0; k0 < DMID; k0 += 32){
    GLDS16(gA + k0,             lA);
    GLDS16(gB + k0,             lB);
    GLDS16(gB + 16 * DMID + k0, lB + 512);
    __syncthreads();
    short8 a[2], b[4];
    for (int m = 0; m < 2; m++)
      a[m] = *(const short8*)&As[(wrow0 + m * 16 + li) * 32 + g * 8];
    for (int n = 0; n < 4; n++)
      b[n] = *(const short8*)&Bs[(wcol0 + n * 16 + li) * 32 + g * 8];
    for (int m = 0; m < 2; m++)
      for (int n = 0; n < 4; n++)
        acc[m][n] = __builtin_amdgcn_mfma_f32_16x16x32_bf16(a[m], b[n], acc[m][n], 0, 0, 0);
    __syncthreads();
  }

  float rsum[2][4] = {{0.f,0.f,0.f,0.f},{0.f,0.f,0.f,0.f}};
  for (int n = 0; n < 4; n++){
    const int col = wcol0 + n * 16 + li;
    const float b1 = ba1[col], w2 = wa2[col];
    for (int m = 0; m < 2; m++){
      f32x4 v = acc[m][n];
      for (int r = 0; r < 4; r++){
        float xv = v[r] + b1;
        float ge = 0.5f * xv * (1.0f + erff(xv * 0.70710678118654752f)); // exact gelu
        rsum[m][r] += ge * w2;
      }
    }
  }
  const float bb = ba2[0];
  for (int m = 0; m < 2; m++){
    for (int r = 0; r < 4; r++){
      float v = rsum[m][r];
      v += __shfl_xor(v, 1); v += __shfl_xor(v, 2);
      v += __shfl_xor(v, 4); v += __shfl_xor(v, 8);
      if (li == 0) s_out[brow + wrow0 + m * 16 + g * 4 + r] = v + bb;
    }
  }
}

// ---------------------------------------------------------------------------
// Softmax weights over 16384 scores.
// ---------------------------------------------------------------------------
__global__ __launch_bounds__(1024) void k_softmax(const float* __restrict__ s,
                                                  float* __restrict__ w){
  __shared__ float red[1024];
  const int t = threadIdx.x;
  float m = -INFINITY;
  for (int i = t; i < LKEEP; i += 1024) m = fmaxf(m, s[i]);
  red[t] = m; __syncthreads();
  for (int st = 512; st > 0; st >>= 1){ if (t < st) red[t] = fmaxf(red[t], red[t + st]); __syncthreads(); }
  m = red[0]; __syncthreads();
  float z = 0.f;
  for (int i = t; i < LKEEP; i += 1024) z += expf(s[i] - m);
  red[t] = z; __syncthreads();
  for (int st = 512; st > 0; st >>= 1){ if (t < st) red[t] += red[t + st]; __syncthreads(); }
  const float invZ = 1.0f / red[0];
  for (int i = t; i < LKEEP; i += 1024) w[i] = expf(s[i] - m) * invZ;
}

// ---------------------------------------------------------------------------
// feat[d] = sum_j w[j] * h[j][d].  8 blocks x 64 cols; bf16x8 loads.
// ---------------------------------------------------------------------------
__global__ __launch_bounds__(256) void k_feat(const u16* __restrict__ hbf,
                                              const float* __restrict__ w,
                                              float* __restrict__ feat){
  const int t = threadIdx.x;
  const int colg = t & 7, rowpar = t >> 3;
  const int c0 = blockIdx.x * 64;
  float acc[8] = {0.f};
  for (int j = rowpar; j < LKEEP; j += 32){
    const float wj = w[j];
    short8 hv = *(const short8*)&hbf[(size_t)j * DMID + c0 + colg * 8];
    for (int c = 0; c < 8; c++) acc[c] += wj * bf2f((u16)hv[c]);
  }
  __shared__ float red[256 * 8];
  for (int c = 0; c < 8; c++) red[t * 8 + c] = acc[c];
  __syncthreads();
  for (int st = 128; st >= 8; st >>= 1){
    if (t < st){ for (int c = 0; c < 8; c++) red[t * 8 + c] += red[(t + st) * 8 + c]; }
    __syncthreads();
  }
  if (t < 8){
    for (int c = 0; c < 8; c++) feat[c0 + t * 8 + c] = red[t * 8 + c];
  }
}

// ---------------------------------------------------------------------------
// Final: logits + soft-CE loss.
// ---------------------------------------------------------------------------
__global__ __launch_bounds__(512) void k_final(const float* __restrict__ feat,
                                               const float* __restrict__ teach,
                                               const float* __restrict__ Wp,
                                               const float* __restrict__ bp,
                                               float* __restrict__ out){
  __shared__ float red[512];
  const int t = threadIdx.x;
  const float f = feat[t];
  const float td = teach[t];

  red[t] = f; __syncthreads();
  for (int st = 256; st > 0; st >>= 1){ if (t < st) red[t] = fmaxf(red[t], red[t + st]); __syncthreads(); }
  const float mf = red[0]; __syncthreads();

  red[t] = td; __syncthreads();
  for (int st = 256; st > 0; st >>= 1){ if (t < st) red[t] = fmaxf(red[t], red[t + st]); __syncthreads(); }
  const float mt = red[0]; __syncthreads();

  red[t] = expf(f - mf); __syncthreads();
  for (int st = 256; st > 0; st >>= 1){ if (t < st) red[t] += red[t + st]; __syncthreads(); }
  const float Zf = red[0]; __syncthreads();

  const float pt = expf(td - mt);
  red[t] = pt; __syncthreads();
  for (int st = 256; st > 0; st >>= 1){ if (t < st) red[t] += red[t + st]; __syncthreads(); }
  const float Zt = red[0]; __syncthreads();

  red[t] = pt * f; __syncthreads();
  for (int st = 256; st > 0; st >>= 1){ if (t < st) red[t] += red[t + st]; __syncthreads(); }
  const float S1 = red[0]; __syncthreads();

  red[t] = f * Wp[t * 2 + 0]; __syncthreads();
  for (int st = 256; st > 0; st >>= 1){ if (t < st) red[t] += red[t + st]; __syncthreads(); }
  const float L0 = red[0]; __syncthreads();

  red[t] = f * Wp[t * 2 + 1]; __syncthreads();
  for (int st = 256; st > 0; st >>= 1){ if (t < st) red[t] += red[t + st]; __syncthreads(); }
  const float L1 = red[0];

  if (t == 0){
    out[0] = L0 + bp[0];
    out[1] = L1 + bp[1];
    out[2] = (mf + logf(Zf)) - S1 / Zt;   // logsumexp(feat) - <softmax(t), feat>
  }
}

// ---------------------------------------------------------------------------
// Launch. ws layout (bytes), total ~49.4 MB (requires ws_size >= 51712000):
//   [0)        keep_ids  int[16384]
//   [65536)    s         f32[16384]
//   [131072)   w         f32[16384]
//   [196608)   feat      f32[512]
//   [200704)   wet       bf16[512][1024]
//   [1249280)  wa1t      bf16[128][512]
//   [1380352)  xbf       bf16[16384][1024]
//   [34934784) hbf       bf16[16384][512]
// ---------------------------------------------------------------------------
extern "C" void kernel_launch(void* const* d_in, const int* in_sizes, int n_in,
                              void* d_out, int out_size, void* d_ws, size_t ws_size,
                              hipStream_t stream){
  const float* x     = (const float*)d_in[0];
  const float* attn  = (const float*)d_in[1];
  const float* teach = (const float*)d_in[2];
  const float* Wemb  = (const float*)d_in[3];
  const float* bemb  = (const float*)d_in[4];
  const float* Wa1   = (const float*)d_in[5];
  const float* ba1   = (const float*)d_in[6];
  const float* Wa2   = (const float*)d_in[7];
  const float* ba2   = (const float*)d_in[8];
  const float* Wp    = (const float*)d_in[9];
  const float* bp    = (const float*)d_in[10];
  float* out = (float*)d_out;

  char* ws = (char*)d_ws;
  int*   keep = (int*)(ws + 0);
  float* s    = (float*)(ws + 65536);
  float* wgt  = (float*)(ws + 131072);
  float* feat = (float*)(ws + 196608);
  u16*   wet  = (u16*)(ws + 200704);
  u16*   wa1t = (u16*)(ws + 200704 + 1048576);
  u16*   xbf  = (u16*)(ws + 200704 + 1048576 + 131072);
  u16*   hbf  = (u16*)(ws + 200704 + 1048576 + 131072 + 33554432);

  k_select<<<dim3(1), dim3(1024), 0, stream>>>(attn, keep);
  k_tcvt<<<dim3(DMID / 32, DIN / 32), dim3(256), 0, stream>>>(Wemb, wet, DIN, DMID);
  k_tcvt<<<dim3(DATT / 32, DMID / 32), dim3(256), 0, stream>>>(Wa1, wa1t, DMID, DATT);
  k_gather<<<dim3(LKEEP), dim3(256), 0, stream>>>(x, keep, xbf);
  k_gemm1<<<dim3(4, 128), dim3(256), 0, stream>>>(xbf, wet, bemb, hbf);
  k_gemm2<<<dim3(LKEEP / 64), dim3(256), 0, stream>>>(hbf, wa1t, ba1, Wa2, ba2, s);
  k_softmax<<<dim3(1), dim3(1024), 0, stream>>>(s, wgt);
  k_feat<<<dim3(8), dim3(256), 0, stream>>>(hbf, wgt, feat);
  k_final<<<dim3(1), dim3(512), 0, stream>>>(feat, teach, Wp, bp, out);
}

// Round 2
// 182.793 us; speedup vs baseline: 1.8664x; 1.8664x over previous
//
#include <hip/hip_runtime.h>
#include <hip/hip_bf16.h>
#include <math.h>

// Problem constants
#define PS    32768
#define DIN   1024
#define DMID  512
#define DATT  128
#define KMASK 16384
#define LKEEP 16384

typedef unsigned short u16;
typedef __attribute__((ext_vector_type(8))) short short8;
typedef __attribute__((ext_vector_type(4))) float f32x4;

__device__ __forceinline__ u16 f2bf(float f){
  unsigned x = __float_as_uint(f);
  unsigned r = (x + 0x7fffu + ((x >> 16) & 1u)) >> 16;  // RNE
  return (u16)r;
}
__device__ __forceinline__ float bf2f(u16 u){
  return __uint_as_float(((unsigned)u) << 16);
}
// monotonic key: larger float -> larger unsigned
__device__ __forceinline__ unsigned fkey(float f){
  unsigned b = __float_as_uint(f);
  return (b & 0x80000000u) ? ~b : (b | 0x80000000u);
}

#define GLDS16(g,l) __builtin_amdgcn_global_load_lds( \
    (const __attribute__((address_space(1))) void*)(g), \
    (__attribute__((address_space(3))) void*)(l), 16, 0, 0)

// ---------------------------------------------------------------------------
// Kernel 1: exact top-K selection (radix-256 select, 4 passes) + compaction.
// keep set = complement of top-KMASK by (value desc, index asc).
// ---------------------------------------------------------------------------
__global__ __launch_bounds__(1024) void k_select(const float* __restrict__ attn,
                                                 int* __restrict__ keep_ids){
  __shared__ unsigned hist[256];
  __shared__ int scan[1024];
  __shared__ unsigned sh_prefix;
  __shared__ int sh_k;
  const int t = threadIdx.x;

  unsigned prefix = 0;
  int k = KMASK;
  for (int p = 0; p < 4; p++){
    const int shift = 24 - 8*p;
    if (t < 256) hist[t] = 0u;
    __syncthreads();
    for (int i = t; i < PS; i += 1024){
      unsigned u = fkey(attn[i]);
      bool match = (p == 0) || ((u >> (shift + 8)) == prefix);
      if (match) atomicAdd(&hist[(u >> shift) & 255u], 1u);
    }
    __syncthreads();
    if (t == 0){
      int cum = 0; int digit = 0;
      for (int b = 255; b >= 0; b--){
        int c = (int)hist[b];
        if (cum + c >= k){ digit = b; k -= cum; break; }
        cum += c;
      }
      sh_prefix = (prefix << 8) | (unsigned)digit;
      sh_k = k;
    }
    __syncthreads();
    prefix = sh_prefix; k = sh_k;
    __syncthreads();
  }
  const unsigned C = prefix;   // cutoff key (KMASK-th largest)
  const int r = k;             // # of ==C elements that go to the MASKED set (smallest indices)

  // chunk of 32 consecutive indices per thread (keeps index order for tie ranks)
  const int base_i = t * 32;

  // pass A: count equals per chunk
  int local_eq = 0;
  for (int j = 0; j < 32; j++){
    if (fkey(attn[base_i + j]) == C) local_eq++;
  }
  scan[t] = local_eq; __syncthreads();
  for (int off = 1; off < 1024; off <<= 1){
    int v = (t >= off) ? scan[t - off] : 0;
    __syncthreads();
    scan[t] += v;
    __syncthreads();
  }
  const int eqbase = scan[t] - local_eq;
  __syncthreads();

  // pass B: kept flags
  unsigned kmask = 0; int local_keep = 0; int eqr = eqbase;
  for (int j = 0; j < 32; j++){
    unsigned u = fkey(attn[base_i + j]);
    bool kept;
    if (u < C) kept = true;
    else if (u == C){ kept = (eqr >= r); eqr++; }
    else kept = false;
    if (kept){ kmask |= (1u << j); local_keep++; }
  }
  scan[t] = local_keep; __syncthreads();
  for (int off = 1; off < 1024; off <<= 1){
    int v = (t >= off) ? scan[t - off] : 0;
    __syncthreads();
    scan[t] += v;
    __syncthreads();
  }
  int wbase = scan[t] - local_keep;

  // pass C: write compacted ids (ascending order)
  for (int j = 0; j < 32; j++){
    if (kmask & (1u << j)) keep_ids[wbase++] = base_i + j;
  }
}

// ---------------------------------------------------------------------------
// Transpose + f32->bf16 convert: out[c][r] = bf16(in[r][c]).  R,C multiples of 32.
// ---------------------------------------------------------------------------
__global__ __launch_bounds__(256) void k_tcvt(const float* __restrict__ in,
                                              u16* __restrict__ out, int R, int C){
  __shared__ float tile[32][33];
  const int tx = threadIdx.x & 31, ty = threadIdx.x >> 5;  // 32 x 8
  const int c0 = blockIdx.x * 32, r0 = blockIdx.y * 32;
  for (int i = 0; i < 32; i += 8)
    tile[ty + i][tx] = in[(size_t)(r0 + ty + i) * C + c0 + tx];
  __syncthreads();
  for (int i = 0; i < 32; i += 8)
    out[(size_t)(c0 + ty + i) * R + r0 + tx] = f2bf(tile[tx][ty + i]);
}

// ---------------------------------------------------------------------------
// Gather kept rows of x and convert to bf16. One block per kept row.
// ---------------------------------------------------------------------------
__global__ __launch_bounds__(256) void k_gather(const float* __restrict__ x,
                                                const int* __restrict__ keep,
                                                u16* __restrict__ xbf){
  const int j = blockIdx.x;
  const int id = keep[j];
  const float4 v = ((const float4*)(x + (size_t)id * DIN))[threadIdx.x];
  ushort4 pk;
  pk.x = f2bf(v.x); pk.y = f2bf(v.y); pk.z = f2bf(v.z); pk.w = f2bf(v.w);
  ((ushort4*)(xbf + (size_t)j * DIN))[threadIdx.x] = pk;
}

// ---------------------------------------------------------------------------
// GEMM1: h = relu(x_k @ W_emb + b_emb)  [16384 x 1024] x [1024 x 512] -> bf16
// 128x128 tile, BK=32, 4 waves (2x2 of 64x64), mfma 16x16x32 bf16.
// A-LDS [128][32] row-major, B-LDS [128 cols][32 k] (W pre-transposed).
// ---------------------------------------------------------------------------
__global__ __launch_bounds__(256) void k_gemm1(const u16* __restrict__ xbf,
                                               const u16* __restrict__ wet,
                                               const float* __restrict__ bemb,
                                               u16* __restrict__ hbf){
  __shared__ __align__(16) u16 As[128 * 32];
  __shared__ __align__(16) u16 Bs[128 * 32];
  const int t = threadIdx.x;
  const int wid = t >> 6, lane = t & 63;
  const int g = lane >> 4, li = lane & 15;
  const int brow = blockIdx.y * 128, bcol = blockIdx.x * 128;
  const int wrow0 = (wid >> 1) * 64, wcol0 = (wid & 1) * 64;

  f32x4 acc[4][4];
  for (int m = 0; m < 4; m++)
    for (int n = 0; n < 4; n++)
      acc[m][n] = (f32x4){0.f, 0.f, 0.f, 0.f};

  const int r4 = lane >> 2, c4 = lane & 3;
  const u16* gA = xbf + ((size_t)(brow + wid * 32 + r4) * DIN + c4 * 8);
  const u16* gB = wet + ((size_t)(bcol + wid * 32 + r4) * DIN + c4 * 8);
  u16* lA = As + wid * 1024;   // wave-uniform LDS base; HW adds lane*16B
  u16* lB = Bs + wid * 1024;

  for (int k0 = 0; k0 < DIN; k0 += 32){
    GLDS16(gA + k0,            lA);        // rows wid*32 + 0..15
    GLDS16(gA + 16 * DIN + k0, lA + 512);  // rows wid*32 + 16..31
    GLDS16(gB + k0,            lB);
    GLDS16(gB + 16 * DIN + k0, lB + 512);
    __syncthreads();
    short8 a[4], b[4];
    for (int m = 0; m < 4; m++)
      a[m] = *(const short8*)&As[(wrow0 + m * 16 + li) * 32 + g * 8];
    for (int n = 0; n < 4; n++)
      b[n] = *(const short8*)&Bs[(wcol0 + n * 16 + li) * 32 + g * 8];
    for (int m = 0; m < 4; m++)
      for (int n = 0; n < 4; n++)
        acc[m][n] = __builtin_amdgcn_mfma_f32_16x16x32_bf16(a[m], b[n], acc[m][n], 0, 0, 0);
    __syncthreads();
  }

  for (int n = 0; n < 4; n++){
    const int col = bcol + wcol0 + n * 16 + li;
    const float be = bemb[col];
    for (int m = 0; m < 4; m++){
      const int row0 = brow + wrow0 + m * 16 + g * 4;
      f32x4 v = acc[m][n];
      for (int r = 0; r < 4; r++){
        float val = v[r] + be;
        if (val < 0.f) val = 0.f;
        hbf[(size_t)(row0 + r) * DMID + col] = f2bf(val);
      }
    }
  }
}

// ---------------------------------------------------------------------------
// GEMM2 + fused exact-gelu + W_a2 dot: s[j] = gelu(h_j @ W_a1 + b_a1) . W_a2 + b_a2
// M-tile 64, N=128 (full), BK=32, 4 waves (2 rows x 2 cols of 32x64).
// ---------------------------------------------------------------------------
__global__ __launch_bounds__(256) void k_gemm2(const u16* __restrict__ hbf,
                                               const u16* __restrict__ wa1t,
                                               const float* __restrict__ ba1,
                                               const float* __restrict__ wa2,
                                               const float* __restrict__ ba2,
                                               float* __restrict__ s_out){
  __shared__ __align__(16) u16 As[64 * 32];
  __shared__ __align__(16) u16 Bs[128 * 32];
  const int t = threadIdx.x;
  const int wid = t >> 6, lane = t & 63;
  const int g = lane >> 4, li = lane & 15;
  const int brow = blockIdx.x * 64;
  const int wrow0 = (wid >> 1) * 32, wcol0 = (wid & 1) * 64;

  f32x4 acc[2][4];
  for (int m = 0; m < 2; m++)
    for (int n = 0; n < 4; n++)
      acc[m][n] = (f32x4){0.f, 0.f, 0.f, 0.f};

  const int r4 = lane >> 2, c4 = lane & 3;
  const u16* gA = hbf  + ((size_t)(brow + wid * 16 + r4) * DMID + c4 * 8);
  const u16* gB = wa1t + ((size_t)(wid * 32 + r4) * DMID + c4 * 8);
  u16* lA = As + wid * 512;
  u16* lB = Bs + wid * 1024;

  for (int k0 = 0; k0 < DMID; k0 += 32){
    GLDS16(gA + k0,             lA);
    GLDS16(gB + k0,             lB);
    GLDS16(gB + 16 * DMID + k0, lB + 512);
    __syncthreads();
    short8 a[2], b[4];
    for (int m = 0; m < 2; m++)
      a[m] = *(const short8*)&As[(wrow0 + m * 16 + li) * 32 + g * 8];
    for (int n = 0; n < 4; n++)
      b[n] = *(const short8*)&Bs[(wcol0 + n * 16 + li) * 32 + g * 8];
    for (int m = 0; m < 2; m++)
      for (int n = 0; n < 4; n++)
        acc[m][n] = __builtin_amdgcn_mfma_f32_16x16x32_bf16(a[m], b[n], acc[m][n], 0, 0, 0);
    __syncthreads();
  }

  float rsum[2][4] = {{0.f,0.f,0.f,0.f},{0.f,0.f,0.f,0.f}};
  for (int n = 0; n < 4; n++){
    const int col = wcol0 + n * 16 + li;
    const float b1 = ba1[col], w2 = wa2[col];
    for (int m = 0; m < 2; m++){
      f32x4 v = acc[m][n];
      for (int r = 0; r < 4; r++){
        float xv = v[r] + b1;
        float ge = 0.5f * xv * (1.0f + erff(xv * 0.70710678118654752f)); // exact gelu
        rsum[m][r] += ge * w2;
      }
    }
  }
  const float bb = ba2[0];
  for (int m = 0; m < 2; m++){
    for (int r = 0; r < 4; r++){
      float v = rsum[m][r];
      v += __shfl_xor(v, 1); v += __shfl_xor(v, 2);
      v += __shfl_xor(v, 4); v += __shfl_xor(v, 8);
      if (li == 0) s_out[brow + wrow0 + m * 16 + g * 4 + r] = v + bb;
    }
  }
}

// ---------------------------------------------------------------------------
// Softmax weights over 16384 scores.
// ---------------------------------------------------------------------------
__global__ __launch_bounds__(1024) void k_softmax(const float* __restrict__ s,
                                                  float* __restrict__ w){
  __shared__ float red[1024];
  const int t = threadIdx.x;
  float m = -INFINITY;
  for (int i = t; i < LKEEP; i += 1024) m = fmaxf(m, s[i]);
  red[t] = m; __syncthreads();
  for (int st = 512; st > 0; st >>= 1){ if (t < st) red[t] = fmaxf(red[t], red[t + st]); __syncthreads(); }
  m = red[0]; __syncthreads();
  float z = 0.f;
  for (int i = t; i < LKEEP; i += 1024) z += expf(s[i] - m);
  red[t] = z; __syncthreads();
  for (int st = 512; st > 0; st >>= 1){ if (t < st) red[t] += red[t + st]; __syncthreads(); }
  const float invZ = 1.0f / red[0];
  for (int i = t; i < LKEEP; i += 1024) w[i] = expf(s[i] - m) * invZ;
}

// ---------------------------------------------------------------------------
// feat[d] = sum_j w[j] * h[j][d]. Two-stage deterministic reduction.
// Stage 1: grid (8 colblk x 64 rowblk); block reduces 256 rows x 64 cols.
// ---------------------------------------------------------------------------
__global__ __launch_bounds__(256) void k_feat1(const u16* __restrict__ hbf,
                                               const float* __restrict__ w,
                                               float* __restrict__ partial){
  const int t = threadIdx.x;
  const int colg = t & 7, rowpar = t >> 3;       // 8 col-groups x 32 row-par
  const int c0 = blockIdx.x * 64;
  const int j0 = blockIdx.y * 256;
  float acc[8] = {0.f};
  for (int j = j0 + rowpar; j < j0 + 256; j += 32){
    const float wj = w[j];
    short8 hv = *(const short8*)&hbf[(size_t)j * DMID + c0 + colg * 8];
    for (int c = 0; c < 8; c++) acc[c] += wj * bf2f((u16)hv[c]);
  }
  __shared__ float red[256 * 8];
  for (int c = 0; c < 8; c++) red[t * 8 + c] = acc[c];
  __syncthreads();
  for (int st = 128; st >= 8; st >>= 1){
    if (t < st){ for (int c = 0; c < 8; c++) red[t * 8 + c] += red[(t + st) * 8 + c]; }
    __syncthreads();
  }
  if (t < 8){
    for (int c = 0; c < 8; c++)
      partial[(size_t)blockIdx.y * DMID + c0 + t * 8 + c] = red[t * 8 + c];
  }
}

// Stage 2: feat[d] = sum_rb partial[rb][d]
__global__ __launch_bounds__(512) void k_feat2(const float* __restrict__ partial,
                                               float* __restrict__ feat){
  const int d = threadIdx.x;
  float s = 0.f;
  for (int rb = 0; rb < 64; rb++) s += partial[(size_t)rb * DMID + d];
  feat[d] = s;
}

// ---------------------------------------------------------------------------
// Final: logits + soft-CE loss.
// ---------------------------------------------------------------------------
__global__ __launch_bounds__(512) void k_final(const float* __restrict__ feat,
                                               const float* __restrict__ teach,
                                               const float* __restrict__ Wp,
                                               const float* __restrict__ bp,
                                               float* __restrict__ out){
  __shared__ float red[512];
  const int t = threadIdx.x;
  const float f = feat[t];
  const float td = teach[t];

  red[t] = f; __syncthreads();
  for (int st = 256; st > 0; st >>= 1){ if (t < st) red[t] = fmaxf(red[t], red[t + st]); __syncthreads(); }
  const float mf = red[0]; __syncthreads();

  red[t] = td; __syncthreads();
  for (int st = 256; st > 0; st >>= 1){ if (t < st) red[t] = fmaxf(red[t], red[t + st]); __syncthreads(); }
  const float mt = red[0]; __syncthreads();

  red[t] = expf(f - mf); __syncthreads();
  for (int st = 256; st > 0; st >>= 1){ if (t < st) red[t] += red[t + st]; __syncthreads(); }
  const float Zf = red[0]; __syncthreads();

  const float pt = expf(td - mt);
  red[t] = pt; __syncthreads();
  for (int st = 256; st > 0; st >>= 1){ if (t < st) red[t] += red[t + st]; __syncthreads(); }
  const float Zt = red[0]; __syncthreads();

  red[t] = pt * f; __syncthreads();
  for (int st = 256; st > 0; st >>= 1){ if (t < st) red[t] += red[t + st]; __syncthreads(); }
  const float S1 = red[0]; __syncthreads();

  red[t] = f * Wp[t * 2 + 0]; __syncthreads();
  for (int st = 256; st > 0; st >>= 1){ if (t < st) red[t] += red[t + st]; __syncthreads(); }
  const float L0 = red[0]; __syncthreads();

  red[t] = f * Wp[t * 2 + 1]; __syncthreads();
  for (int st = 256; st > 0; st >>= 1){ if (t < st) red[t] += red[t + st]; __syncthreads(); }
  const float L1 = red[0];

  if (t == 0){
    out[0] = L0 + bp[0];
    out[1] = L1 + bp[1];
    out[2] = (mf + logf(Zf)) - S1 / Zt;   // logsumexp(feat) - <softmax(t), feat>
  }
}

// ---------------------------------------------------------------------------
// Launch. ws layout (bytes), total ~49.4 MB:
//   [0)        keep_ids  int[16384]
//   [65536)    s         f32[16384]
//   [131072)   w         f32[16384]
//   [196608)   feat      f32[512]
//   [200704)   wet       bf16[512][1024]
//   [1249280)  wa1t      bf16[128][512]
//   [1380352)  xbf       bf16[16384][1024]   (dead after k_gemm1; reused as partial)
//   [34934784) hbf       bf16[16384][512]
// ---------------------------------------------------------------------------
extern "C" void kernel_launch(void* const* d_in, const int* in_sizes, int n_in,
                              void* d_out, int out_size, void* d_ws, size_t ws_size,
                              hipStream_t stream){
  const float* x     = (const float*)d_in[0];
  const float* attn  = (const float*)d_in[1];
  const float* teach = (const float*)d_in[2];
  const float* Wemb  = (const float*)d_in[3];
  const float* bemb  = (const float*)d_in[4];
  const float* Wa1   = (const float*)d_in[5];
  const float* ba1   = (const float*)d_in[6];
  const float* Wa2   = (const float*)d_in[7];
  const float* ba2   = (const float*)d_in[8];
  const float* Wp    = (const float*)d_in[9];
  const float* bp    = (const float*)d_in[10];
  float* out = (float*)d_out;

  char* ws = (char*)d_ws;
  int*   keep = (int*)(ws + 0);
  float* s    = (float*)(ws + 65536);
  float* wgt  = (float*)(ws + 131072);
  float* feat = (float*)(ws + 196608);
  u16*   wet  = (u16*)(ws + 200704);
  u16*   wa1t = (u16*)(ws + 200704 + 1048576);
  u16*   xbf  = (u16*)(ws + 200704 + 1048576 + 131072);
  u16*   hbf  = (u16*)(ws + 200704 + 1048576 + 131072 + 33554432);
  float* partial = (float*)xbf;   // xbf region is dead after k_gemm1

  k_select<<<dim3(1), dim3(1024), 0, stream>>>(attn, keep);
  k_tcvt<<<dim3(DMID / 32, DIN / 32), dim3(256), 0, stream>>>(Wemb, wet, DIN, DMID);
  k_tcvt<<<dim3(DATT / 32, DMID / 32), dim3(256), 0, stream>>>(Wa1, wa1t, DMID, DATT);
  k_gather<<<dim3(LKEEP), dim3(256), 0, stream>>>(x, keep, xbf);
  k_gemm1<<<dim3(4, 128), dim3(256), 0, stream>>>(xbf, wet, bemb, hbf);
  k_gemm2<<<dim3(LKEEP / 64), dim3(256), 0, stream>>>(hbf, wa1t, ba1, Wa2, ba2, s);
  k_softmax<<<dim3(1), dim3(1024), 0, stream>>>(s, wgt);
  k_feat1<<<dim3(8, 64), dim3(256), 0, stream>>>(hbf, wgt, partial);
  k_feat2<<<dim3(1), dim3(512), 0, stream>>>(partial, feat);
  k_final<<<dim3(1), dim3(512), 0, stream>>>(feat, teach, Wp, bp, out);
}

// Round 3
// 159.302 us; speedup vs baseline: 2.1416x; 1.1475x over previous
//
#include <hip/hip_runtime.h>
#include <hip/hip_bf16.h>
#include <math.h>

// Problem constants
#define PS    32768
#define DIN   1024
#define DMID  512
#define DATT  128
#define KMASK 16384
#define LKEEP 16384

typedef unsigned short u16;
typedef __attribute__((ext_vector_type(8))) short short8;
typedef __attribute__((ext_vector_type(4))) float f32x4;

__device__ __forceinline__ u16 f2bf(float f){
  unsigned x = __float_as_uint(f);
  unsigned r = (x + 0x7fffu + ((x >> 16) & 1u)) >> 16;  // RNE
  return (u16)r;
}
__device__ __forceinline__ float bf2f(u16 u){
  return __uint_as_float(((unsigned)u) << 16);
}
// monotonic key: larger float -> larger unsigned
__device__ __forceinline__ unsigned fkey(float f){
  unsigned b = __float_as_uint(f);
  return (b & 0x80000000u) ? ~b : (b | 0x80000000u);
}

#define GLDS16(g,l) __builtin_amdgcn_global_load_lds( \
    (const __attribute__((address_space(1))) void*)(g), \
    (__attribute__((address_space(3))) void*)(l), 16, 0, 0)

// ---------------------------------------------------------------------------
// Selection pipeline. ctrl layout (ints): [0]=B, [1]=kprime, [2]=C (as uint),
// [3]=eqidx_thr, [4..36)=blockcnt[32]. hist = int[16384].
// keep set = complement of top-KMASK by (value desc, index asc), i.e.
// kept(u,idx) = (u < C) || (u == C && idx > eqidx_thr).
// ---------------------------------------------------------------------------

// Stage 1: 14-bit global histogram. 32 blocks x 1024, 1 element/thread.
__global__ __launch_bounds__(1024) void k_sel_hist(const float* __restrict__ attn,
                                                   int* __restrict__ hist){
  const int i = blockIdx.x * 1024 + threadIdx.x;
  const unsigned u = fkey(attn[i]);
  atomicAdd(&hist[u >> 18], 1);
}

// Stage 2: suffix-scan 16384 bins, find cutoff bin B and rank-in-bin kprime.
__global__ __launch_bounds__(1024) void k_sel_scan(const int* __restrict__ hist,
                                                   int* __restrict__ ctrl){
  __shared__ int suf[1024];
  const int t = threadIdx.x;
  int local[16]; int s = 0;
  const int base = t * 16;
  for (int j = 0; j < 16; j++){ local[j] = hist[base + j]; s += local[j]; }
  suf[t] = s; __syncthreads();
  for (int off = 1; off < 1024; off <<= 1){
    int v = (t + off < 1024) ? suf[t + off] : 0;
    __syncthreads();
    suf[t] += v;
    __syncthreads();
  }
  // suf[t] = sum over bins of threads >= t
  const int above = (t < 1023) ? suf[t + 1] : 0;
  if (above < KMASK && KMASK <= suf[t]){
    int cum = above;
    for (int b = 15; b >= 0; b--){
      int c = local[b];
      if (cum + c >= KMASK){ ctrl[0] = base + b; ctrl[1] = KMASK - cum; break; }
      cum += c;
    }
  }
}

// Stage 3: refine within bin B via two 9-bit passes -> exact C, r, eqidx_thr.
__global__ __launch_bounds__(1024) void k_sel_refine(const float* __restrict__ attn,
                                                     int* __restrict__ ctrl){
  __shared__ int h[512];
  __shared__ int sh_d, sh_k;
  __shared__ int eqn;
  __shared__ int eqidx[1024];
  __shared__ int sh_thr;
  const int t = threadIdx.x;
  const unsigned B = (unsigned)ctrl[0];
  const int kp = ctrl[1];

  // pass 1: histogram of bits [17:9] among elements in bin B
  if (t < 512) h[t] = 0;
  __syncthreads();
  for (int i = t; i < PS; i += 1024){
    unsigned u = fkey(attn[i]);
    if ((u >> 18) == B) atomicAdd(&h[(u >> 9) & 511u], 1);
  }
  __syncthreads();
  // suffix scan of 512
  for (int off = 1; off < 512; off <<= 1){
    int v = (t < 512 && t + off < 512) ? h[t + off] : 0;
    __syncthreads();
    if (t < 512) h[t] += v;
    __syncthreads();
  }
  // h[d] now = count of digits >= d... (we destroyed raw counts; recover via h[d]-h[d+1])
  if (t < 512){
    int above = (t < 511) ? h[t + 1] : 0;
    if (above < kp && kp <= h[t]){ sh_d = t; sh_k = kp - above; }
  }
  __syncthreads();
  const int d1 = sh_d, k2 = sh_k;
  __syncthreads();

  // pass 2: histogram of bits [8:0] among elements matching (B, d1)
  if (t < 512) h[t] = 0;
  __syncthreads();
  const unsigned pref = (B << 9) | (unsigned)d1;
  for (int i = t; i < PS; i += 1024){
    unsigned u = fkey(attn[i]);
    if ((u >> 9) == pref) atomicAdd(&h[u & 511u], 1);
  }
  __syncthreads();
  for (int off = 1; off < 512; off <<= 1){
    int v = (t < 512 && t + off < 512) ? h[t + off] : 0;
    __syncthreads();
    if (t < 512) h[t] += v;
    __syncthreads();
  }
  if (t < 512){
    int above = (t < 511) ? h[t + 1] : 0;
    if (above < k2 && k2 <= h[t]){ sh_d = t; sh_k = k2 - above; }
  }
  if (t == 0) eqn = 0;
  __syncthreads();
  const unsigned C = (pref << 9) | (unsigned)sh_d;
  const int r = sh_k;     // r >= 1 elements == C are masked (smallest indices)
  __syncthreads();

  // pass 3: collect indices of elements == C
  for (int i = t; i < PS; i += 1024){
    if (fkey(attn[i]) == C){
      int p = atomicAdd(&eqn, 1);
      if (p < 1024) eqidx[p] = i;
    }
  }
  __syncthreads();
  const int n = (eqn < 1024) ? eqn : 1024;
  // eqidx_thr = r-th smallest index among the n collected (rank r-1 ascending)
  if (t < n){
    int me = eqidx[t];
    int rank = 0;
    for (int j = 0; j < n; j++) rank += (eqidx[j] < me);
    if (rank == r - 1) sh_thr = me;
  }
  __syncthreads();
  if (t == 0){ ctrl[2] = (int)C; ctrl[3] = sh_thr; }
}

// Stage 4: per-block keep counts (32 blocks x 1024).
__global__ __launch_bounds__(1024) void k_sel_cnt(const float* __restrict__ attn,
                                                  int* __restrict__ ctrl){
  __shared__ int wc[16];
  const int t = threadIdx.x;
  const int i = blockIdx.x * 1024 + t;
  const unsigned C = (unsigned)ctrl[2];
  const int thr = ctrl[3];
  const unsigned u = fkey(attn[i]);
  const bool kept = (u < C) || (u == C && i > thr);
  unsigned long long b = __ballot(kept);
  const int lane = t & 63, w = t >> 6;
  if (lane == 0) wc[w] = __popcll(b);
  __syncthreads();
  if (t == 0){
    int s = 0;
    for (int j = 0; j < 16; j++) s += wc[j];
    ctrl[4 + blockIdx.x] = s;
  }
}

// Stage 5: stable compacted write of keep ids.
__global__ __launch_bounds__(1024) void k_sel_write(const float* __restrict__ attn,
                                                    const int* __restrict__ ctrl,
                                                    int* __restrict__ keep_ids){
  __shared__ int wbase[16];
  __shared__ int sh_base;
  const int t = threadIdx.x;
  const int i = blockIdx.x * 1024 + t;
  const unsigned C = (unsigned)ctrl[2];
  const int thr = ctrl[3];
  const unsigned u = fkey(attn[i]);
  const bool kept = (u < C) || (u == C && i > thr);
  unsigned long long b = __ballot(kept);
  const int lane = t & 63, w = t >> 6;
  if (lane == 0) wbase[w] = __popcll(b);
  __syncthreads();
  if (t == 0){
    int base = 0;
    for (int j = 0; j < (int)blockIdx.x; j++) base += ctrl[4 + j];
    sh_base = base;
    int run = 0;
    for (int j = 0; j < 16; j++){ int c = wbase[j]; wbase[j] = run; run += c; }
  }
  __syncthreads();
  if (kept){
    const int lanerank = __popcll(b & ((1ull << lane) - 1ull));
    keep_ids[sh_base + wbase[w] + lanerank] = i;
  }
}

// ---------------------------------------------------------------------------
// Transpose + f32->bf16 convert: out[c][r] = bf16(in[r][c]).  R,C multiples of 32.
// Optionally zeros zbuf[0..zn) (flat across grid) for the selection pipeline.
// ---------------------------------------------------------------------------
__global__ __launch_bounds__(256) void k_tcvt(const float* __restrict__ in,
                                              u16* __restrict__ out, int R, int C,
                                              int* __restrict__ zbuf, int zn){
  __shared__ float tile[32][33];
  const int flat = blockIdx.y * gridDim.x * 256 + blockIdx.x * 256 + threadIdx.x;
  if (zbuf && flat < zn) zbuf[flat] = 0;
  const int tx = threadIdx.x & 31, ty = threadIdx.x >> 5;  // 32 x 8
  const int c0 = blockIdx.x * 32, r0 = blockIdx.y * 32;
  for (int i = 0; i < 32; i += 8)
    tile[ty + i][tx] = in[(size_t)(r0 + ty + i) * C + c0 + tx];
  __syncthreads();
  for (int i = 0; i < 32; i += 8)
    out[(size_t)(c0 + ty + i) * R + r0 + tx] = f2bf(tile[tx][ty + i]);
}

// ---------------------------------------------------------------------------
// Gather kept rows of x and convert to bf16. One block per kept row.
// ---------------------------------------------------------------------------
__global__ __launch_bounds__(256) void k_gather(const float* __restrict__ x,
                                                const int* __restrict__ keep,
                                                u16* __restrict__ xbf){
  const int j = blockIdx.x;
  const int id = keep[j];
  const float4 v = ((const float4*)(x + (size_t)id * DIN))[threadIdx.x];
  ushort4 pk;
  pk.x = f2bf(v.x); pk.y = f2bf(v.y); pk.z = f2bf(v.z); pk.w = f2bf(v.w);
  ((ushort4*)(xbf + (size_t)j * DIN))[threadIdx.x] = pk;
}

// ---------------------------------------------------------------------------
// GEMM1: h = relu(x_k @ W_emb + b_emb)  [16384 x 1024] x [1024 x 512] -> bf16
// 128x128 tile, BK=32, 4 waves (2x2 of 64x64), mfma 16x16x32 bf16.
// ---------------------------------------------------------------------------
__global__ __launch_bounds__(256) void k_gemm1(const u16* __restrict__ xbf,
                                               const u16* __restrict__ wet,
                                               const float* __restrict__ bemb,
                                               u16* __restrict__ hbf){
  __shared__ __align__(16) u16 As[128 * 32];
  __shared__ __align__(16) u16 Bs[128 * 32];
  const int t = threadIdx.x;
  const int wid = t >> 6, lane = t & 63;
  const int g = lane >> 4, li = lane & 15;
  const int brow = blockIdx.y * 128, bcol = blockIdx.x * 128;
  const int wrow0 = (wid >> 1) * 64, wcol0 = (wid & 1) * 64;

  f32x4 acc[4][4];
  for (int m = 0; m < 4; m++)
    for (int n = 0; n < 4; n++)
      acc[m][n] = (f32x4){0.f, 0.f, 0.f, 0.f};

  const int r4 = lane >> 2, c4 = lane & 3;
  const u16* gA = xbf + ((size_t)(brow + wid * 32 + r4) * DIN + c4 * 8);
  const u16* gB = wet + ((size_t)(bcol + wid * 32 + r4) * DIN + c4 * 8);
  u16* lA = As + wid * 1024;   // wave-uniform LDS base; HW adds lane*16B
  u16* lB = Bs + wid * 1024;

  for (int k0 = 0; k0 < DIN; k0 += 32){
    GLDS16(gA + k0,            lA);        // rows wid*32 + 0..15
    GLDS16(gA + 16 * DIN + k0, lA + 512);  // rows wid*32 + 16..31
    GLDS16(gB + k0,            lB);
    GLDS16(gB + 16 * DIN + k0, lB + 512);
    __syncthreads();
    short8 a[4], b[4];
    for (int m = 0; m < 4; m++)
      a[m] = *(const short8*)&As[(wrow0 + m * 16 + li) * 32 + g * 8];
    for (int n = 0; n < 4; n++)
      b[n] = *(const short8*)&Bs[(wcol0 + n * 16 + li) * 32 + g * 8];
    for (int m = 0; m < 4; m++)
      for (int n = 0; n < 4; n++)
        acc[m][n] = __builtin_amdgcn_mfma_f32_16x16x32_bf16(a[m], b[n], acc[m][n], 0, 0, 0);
    __syncthreads();
  }

  for (int n = 0; n < 4; n++){
    const int col = bcol + wcol0 + n * 16 + li;
    const float be = bemb[col];
    for (int m = 0; m < 4; m++){
      const int row0 = brow + wrow0 + m * 16 + g * 4;
      f32x4 v = acc[m][n];
      for (int r = 0; r < 4; r++){
        float val = v[r] + be;
        if (val < 0.f) val = 0.f;
        hbf[(size_t)(row0 + r) * DMID + col] = f2bf(val);
      }
    }
  }
}

// ---------------------------------------------------------------------------
// GEMM2 + fused exact-gelu + W_a2 dot: s[j] = gelu(h_j @ W_a1 + b_a1) . W_a2 + b_a2
// ---------------------------------------------------------------------------
__global__ __launch_bounds__(256) void k_gemm2(const u16* __restrict__ hbf,
                                               const u16* __restrict__ wa1t,
                                               const float* __restrict__ ba1,
                                               const float* __restrict__ wa2,
                                               const float* __restrict__ ba2,
                                               float* __restrict__ s_out){
  __shared__ __align__(16) u16 As[64 * 32];
  __shared__ __align__(16) u16 Bs[128 * 32];
  const int t = threadIdx.x;
  const int wid = t >> 6, lane = t & 63;
  const int g = lane >> 4, li = lane & 15;
  const int brow = blockIdx.x * 64;
  const int wrow0 = (wid >> 1) * 32, wcol0 = (wid & 1) * 64;

  f32x4 acc[2][4];
  for (int m = 0; m < 2; m++)
    for (int n = 0; n < 4; n++)
      acc[m][n] = (f32x4){0.f, 0.f, 0.f, 0.f};

  const int r4 = lane >> 2, c4 = lane & 3;
  const u16* gA = hbf  + ((size_t)(brow + wid * 16 + r4) * DMID + c4 * 8);
  const u16* gB = wa1t + ((size_t)(wid * 32 + r4) * DMID + c4 * 8);
  u16* lA = As + wid * 512;
  u16* lB = Bs + wid * 1024;

  for (int k0 = 0; k0 < DMID; k0 += 32){
    GLDS16(gA + k0,             lA);
    GLDS16(gB + k0,             lB);
    GLDS16(gB + 16 * DMID + k0, lB + 512);
    __syncthreads();
    short8 a[2], b[4];
    for (int m = 0; m < 2; m++)
      a[m] = *(const short8*)&As[(wrow0 + m * 16 + li) * 32 + g * 8];
    for (int n = 0; n < 4; n++)
      b[n] = *(const short8*)&Bs[(wcol0 + n * 16 + li) * 32 + g * 8];
    for (int m = 0; m < 2; m++)
      for (int n = 0; n < 4; n++)
        acc[m][n] = __builtin_amdgcn_mfma_f32_16x16x32_bf16(a[m], b[n], acc[m][n], 0, 0, 0);
    __syncthreads();
  }

  float rsum[2][4] = {{0.f,0.f,0.f,0.f},{0.f,0.f,0.f,0.f}};
  for (int n = 0; n < 4; n++){
    const int col = wcol0 + n * 16 + li;
    const float b1 = ba1[col], w2 = wa2[col];
    for (int m = 0; m < 2; m++){
      f32x4 v = acc[m][n];
      for (int r = 0; r < 4; r++){
        float xv = v[r] + b1;
        float ge = 0.5f * xv * (1.0f + erff(xv * 0.70710678118654752f)); // exact gelu
        rsum[m][r] += ge * w2;
      }
    }
  }
  const float bb = ba2[0];
  for (int m = 0; m < 2; m++){
    for (int r = 0; r < 4; r++){
      float v = rsum[m][r];
      v += __shfl_xor(v, 1); v += __shfl_xor(v, 2);
      v += __shfl_xor(v, 4); v += __shfl_xor(v, 8);
      if (li == 0) s_out[brow + wrow0 + m * 16 + g * 4 + r] = v + bb;
    }
  }
}

// ---------------------------------------------------------------------------
// Softmax weights over 16384 scores.
// ---------------------------------------------------------------------------
__global__ __launch_bounds__(1024) void k_softmax(const float* __restrict__ s,
                                                  float* __restrict__ w){
  __shared__ float red[1024];
  const int t = threadIdx.x;
  float m = -INFINITY;
  for (int i = t; i < LKEEP; i += 1024) m = fmaxf(m, s[i]);
  red[t] = m; __syncthreads();
  for (int st = 512; st > 0; st >>= 1){ if (t < st) red[t] = fmaxf(red[t], red[t + st]); __syncthreads(); }
  m = red[0]; __syncthreads();
  float z = 0.f;
  for (int i = t; i < LKEEP; i += 1024) z += expf(s[i] - m);
  red[t] = z; __syncthreads();
  for (int st = 512; st > 0; st >>= 1){ if (t < st) red[t] += red[t + st]; __syncthreads(); }
  const float invZ = 1.0f / red[0];
  for (int i = t; i < LKEEP; i += 1024) w[i] = expf(s[i] - m) * invZ;
}

// ---------------------------------------------------------------------------
// feat[d] = sum_j w[j] * h[j][d]. Two-stage deterministic reduction.
// ---------------------------------------------------------------------------
__global__ __launch_bounds__(256) void k_feat1(const u16* __restrict__ hbf,
                                               const float* __restrict__ w,
                                               float* __restrict__ partial){
  const int t = threadIdx.x;
  const int colg = t & 7, rowpar = t >> 3;       // 8 col-groups x 32 row-par
  const int c0 = blockIdx.x * 64;
  const int j0 = blockIdx.y * 256;
  float acc[8] = {0.f};
  for (int j = j0 + rowpar; j < j0 + 256; j += 32){
    const float wj = w[j];
    short8 hv = *(const short8*)&hbf[(size_t)j * DMID + c0 + colg * 8];
    for (int c = 0; c < 8; c++) acc[c] += wj * bf2f((u16)hv[c]);
  }
  __shared__ float red[256 * 8];
  for (int c = 0; c < 8; c++) red[t * 8 + c] = acc[c];
  __syncthreads();
  for (int st = 128; st >= 8; st >>= 1){
    if (t < st){ for (int c = 0; c < 8; c++) red[t * 8 + c] += red[(t + st) * 8 + c]; }
    __syncthreads();
  }
  if (t < 8){
    for (int c = 0; c < 8; c++)
      partial[(size_t)blockIdx.y * DMID + c0 + t * 8 + c] = red[t * 8 + c];
  }
}

__global__ __launch_bounds__(512) void k_feat2(const float* __restrict__ partial,
                                               float* __restrict__ feat){
  const int d = threadIdx.x;
  float s = 0.f;
  for (int rb = 0; rb < 64; rb++) s += partial[(size_t)rb * DMID + d];
  feat[d] = s;
}

// ---------------------------------------------------------------------------
// Final: logits + soft-CE loss.
// ---------------------------------------------------------------------------
__global__ __launch_bounds__(512) void k_final(const float* __restrict__ feat,
                                               const float* __restrict__ teach,
                                               const float* __restrict__ Wp,
                                               const float* __restrict__ bp,
                                               float* __restrict__ out){
  __shared__ float red[512];
  const int t = threadIdx.x;
  const float f = feat[t];
  const float td = teach[t];

  red[t] = f; __syncthreads();
  for (int st = 256; st > 0; st >>= 1){ if (t < st) red[t] = fmaxf(red[t], red[t + st]); __syncthreads(); }
  const float mf = red[0]; __syncthreads();

  red[t] = td; __syncthreads();
  for (int st = 256; st > 0; st >>= 1){ if (t < st) red[t] = fmaxf(red[t], red[t + st]); __syncthreads(); }
  const float mt = red[0]; __syncthreads();

  red[t] = expf(f - mf); __syncthreads();
  for (int st = 256; st > 0; st >>= 1){ if (t < st) red[t] += red[t + st]; __syncthreads(); }
  const float Zf = red[0]; __syncthreads();

  const float pt = expf(td - mt);
  red[t] = pt; __syncthreads();
  for (int st = 256; st > 0; st >>= 1){ if (t < st) red[t] += red[t + st]; __syncthreads(); }
  const float Zt = red[0]; __syncthreads();

  red[t] = pt * f; __syncthreads();
  for (int st = 256; st > 0; st >>= 1){ if (t < st) red[t] += red[t + st]; __syncthreads(); }
  const float S1 = red[0]; __syncthreads();

  red[t] = f * Wp[t * 2 + 0]; __syncthreads();
  for (int st = 256; st > 0; st >>= 1){ if (t < st) red[t] += red[t + st]; __syncthreads(); }
  const float L0 = red[0]; __syncthreads();

  red[t] = f * Wp[t * 2 + 1]; __syncthreads();
  for (int st = 256; st > 0; st >>= 1){ if (t < st) red[t] += red[t + st]; __syncthreads(); }
  const float L1 = red[0];

  if (t == 0){
    out[0] = L0 + bp[0];
    out[1] = L1 + bp[1];
    out[2] = (mf + logf(Zf)) - S1 / Zt;   // logsumexp(feat) - <softmax(t), feat>
  }
}

// ---------------------------------------------------------------------------
// Launch. ws layout (bytes), total ~49.4 MB:
//   [0)        keep_ids  int[16384]
//   [65536)    s         f32[16384]
//   [131072)   w         f32[16384]
//   [196608)   feat      f32[512]
//   [200704)   wet       bf16[512][1024]
//   [1249280)  wa1t      bf16[128][512]
//   [1380352)  xbf       bf16[16384][1024]
//              (front of xbf doubles as hist[16384]+ctrl[64] during selection,
//               then as partial[64][512] for k_feat1 — all disjoint in time)
//   [34934784) hbf       bf16[16384][512]
// ---------------------------------------------------------------------------
extern "C" void kernel_launch(void* const* d_in, const int* in_sizes, int n_in,
                              void* d_out, int out_size, void* d_ws, size_t ws_size,
                              hipStream_t stream){
  const float* x     = (const float*)d_in[0];
  const float* attn  = (const float*)d_in[1];
  const float* teach = (const float*)d_in[2];
  const float* Wemb  = (const float*)d_in[3];
  const float* bemb  = (const float*)d_in[4];
  const float* Wa1   = (const float*)d_in[5];
  const float* ba1   = (const float*)d_in[6];
  const float* Wa2   = (const float*)d_in[7];
  const float* ba2   = (const float*)d_in[8];
  const float* Wp    = (const float*)d_in[9];
  const float* bp    = (const float*)d_in[10];
  float* out = (float*)d_out;

  char* ws = (char*)d_ws;
  int*   keep = (int*)(ws + 0);
  float* s    = (float*)(ws + 65536);
  float* wgt  = (float*)(ws + 131072);
  float* feat = (float*)(ws + 196608);
  u16*   wet  = (u16*)(ws + 200704);
  u16*   wa1t = (u16*)(ws + 200704 + 1048576);
  u16*   xbf  = (u16*)(ws + 200704 + 1048576 + 131072);
  u16*   hbf  = (u16*)(ws + 200704 + 1048576 + 131072 + 33554432);
  float* partial = (float*)xbf;          // xbf region dead after k_gemm1
  int*   hist = (int*)xbf;               // xbf region dead before k_gather
  int*   ctrl = hist + 16384;

  // selection pipeline (hist+ctrl zeroed for free inside k_tcvt of Wemb)
  k_tcvt<<<dim3(DMID / 32, DIN / 32), dim3(256), 0, stream>>>(Wemb, wet, DIN, DMID, hist, 16384 + 64);
  k_sel_hist<<<dim3(32), dim3(1024), 0, stream>>>(attn, hist);
  k_sel_scan<<<dim3(1), dim3(1024), 0, stream>>>(hist, ctrl);
  k_sel_refine<<<dim3(1), dim3(1024), 0, stream>>>(attn, ctrl);
  k_sel_cnt<<<dim3(32), dim3(1024), 0, stream>>>(attn, ctrl);
  k_sel_write<<<dim3(32), dim3(1024), 0, stream>>>(attn, ctrl, keep);

  k_tcvt<<<dim3(DATT / 32, DMID / 32), dim3(256), 0, stream>>>(Wa1, wa1t, DMID, DATT, (int*)nullptr, 0);
  k_gather<<<dim3(LKEEP), dim3(256), 0, stream>>>(x, keep, xbf);
  k_gemm1<<<dim3(4, 128), dim3(256), 0, stream>>>(xbf, wet, bemb, hbf);
  k_gemm2<<<dim3(LKEEP / 64), dim3(256), 0, stream>>>(hbf, wa1t, ba1, Wa2, ba2, s);
  k_softmax<<<dim3(1), dim3(1024), 0, stream>>>(s, wgt);
  k_feat1<<<dim3(8, 64), dim3(256), 0, stream>>>(hbf, wgt, partial);
  k_feat2<<<dim3(1), dim3(512), 0, stream>>>(partial, feat);
  k_final<<<dim3(1), dim3(512), 0, stream>>>(feat, teach, Wp, bp, out);
}